// Round 1
// baseline (10093.347 us; speedup 1.0000x reference)
//
#include <hip/hip_runtime.h>

#define B_ 64
#define S_ 2048
#define I_ 512
#define H_ 512

typedef _Float16 half2v __attribute__((ext_vector_type(2)));
typedef _Float16 half8v __attribute__((ext_vector_type(8)));
typedef float    float4v __attribute__((ext_vector_type(4)));
typedef unsigned int uint4v __attribute__((ext_vector_type(4)));
typedef unsigned short ushort_t;

__device__ inline unsigned int pk2(float a, float b) {
    // v_cvt_pkrtz_f16_f32: pack (a->low, b->high)
    return __builtin_bit_cast(unsigned int, __builtin_amdgcn_cvt_pkrtz(a, b));
}

__device__ inline uint4v pack8(float4v a, float4v b) {
    uint4v r;
    r.x = pk2(a.x, a.y);
    r.y = pk2(a.z, a.w);
    r.z = pk2(b.x, b.y);
    r.w = pk2(b.z, b.w);
    return r;
}

__device__ inline float fdot2u(unsigned int h2, unsigned int w2, float acc) {
    return __builtin_amdgcn_fdot2(__builtin_bit_cast(half2v, h2),
                                  __builtin_bit_cast(half2v, w2), acc, false);
}

// ---------------------------------------------------------------------------
// Kernel 1: xp[m, n] = sum_k inputs[m, k] * W_ih[n, k] + b_ih[n]
// M = 131072, N = 512, K = 512.  Tile: BM=64, BN=512 (A read exactly once),
// BK=32, fp16 MFMA 16x16x32 with fp32 accumulate. Written into d_out where
// the scan kernel later overwrites each [b,t,:] slot with h.
// ---------------------------------------------------------------------------
__global__ __launch_bounds__(256, 2) void xproj_gemm(
    const float* __restrict__ A,    // [131072, 512] inputs
    const float* __restrict__ Bw,   // [512, 512]    W_ih
    const float* __restrict__ bias, // [512]         b_ih
    float* __restrict__ C)          // [131072, 512] -> d_out
{
    // LDS tiles, fp16, row stride 5*16B = 80B (pad + xor swizzle breaks conflicts)
    __shared__ uint4v As[64 * 5];
    __shared__ uint4v Bs[512 * 5];

    const int tid  = threadIdx.x;
    const int wave = tid >> 6;
    const int lane = tid & 63;
    const int lm   = lane & 15;   // MFMA: A/B frag non-K index
    const int lq   = lane >> 4;   // MFMA: k-quarter
    const int m0   = blockIdx.x * 64;
    const int nb   = wave * 128;  // each wave owns 128 cols

    float4v acc[4][8];
#pragma unroll
    for (int mf = 0; mf < 4; ++mf)
#pragma unroll
        for (int nf = 0; nf < 8; ++nf)
            acc[mf][nf] = (float4v){0.f, 0.f, 0.f, 0.f};

    float biasv[8];
#pragma unroll
    for (int nf = 0; nf < 8; ++nf)
        biasv[nf] = bias[nb + nf * 16 + lm];

    const int sm    = tid >> 2;            // staging row 0..63
    const int skq   = tid & 3;             // staging k-quarter
    const int sslot = skq ^ (sm & 3);      // xor swizzle (row&3 invariant mod 64)

    for (int kt = 0; kt < 16; ++kt) {
        const int k0 = kt * 32;
        // --- global fp32 loads ---
        const float* ap = A + (size_t)(m0 + sm) * 512 + k0 + skq * 8;
        float4v a0 = *(const float4v*)ap;
        float4v a1 = *(const float4v*)(ap + 4);
        float4v b0[8], b1[8];
#pragma unroll
        for (int i = 0; i < 8; ++i) {
            const float* bp = Bw + (size_t)(sm + 64 * i) * 512 + k0 + skq * 8;
            b0[i] = *(const float4v*)bp;
            b1[i] = *(const float4v*)(bp + 4);
        }
        __syncthreads();  // prior iter frag reads done
        As[sm * 5 + sslot] = pack8(a0, a1);
#pragma unroll
        for (int i = 0; i < 8; ++i)
            Bs[(sm + 64 * i) * 5 + sslot] = pack8(b0[i], b1[i]);
        __syncthreads();

        // --- fragments + MFMA ---
        half8v af[4];
#pragma unroll
        for (int mf = 0; mf < 4; ++mf) {
            int row = mf * 16 + lm;
            af[mf] = __builtin_bit_cast(half8v, As[row * 5 + (lq ^ (lm & 3))]);
        }
        half8v bfr[8];
#pragma unroll
        for (int nf = 0; nf < 8; ++nf) {
            int row = nb + nf * 16 + lm;
            bfr[nf] = __builtin_bit_cast(half8v, Bs[row * 5 + (lq ^ (lm & 3))]);
        }
#pragma unroll
        for (int mf = 0; mf < 4; ++mf)
#pragma unroll
            for (int nf = 0; nf < 8; ++nf)
                acc[mf][nf] = __builtin_amdgcn_mfma_f32_16x16x32_f16(
                    af[mf], bfr[nf], acc[mf][nf], 0, 0, 0);
    }

    // epilogue: C/D layout col = lane&15, row = (lane>>4)*4 + reg
#pragma unroll
    for (int mf = 0; mf < 4; ++mf) {
        int mrow = m0 + mf * 16 + lq * 4;
#pragma unroll
        for (int nf = 0; nf < 8; ++nf) {
            float* cp = C + (size_t)mrow * 512 + nb + nf * 16 + lm;
            float4v v = acc[mf][nf];
            cp[0]    = v.x + biasv[nf];
            cp[512]  = v.y + biasv[nf];
            cp[1024] = v.z + biasv[nf];
            cp[1536] = v.w + biasv[nf];
        }
    }
}

// ---------------------------------------------------------------------------
// Kernel 2: the sequential scan. One workgroup per batch (64 WGs x 512 thr).
// Thread j owns output row j: h_new[j] = tanh(xp[j] + b_hh[j] + W[j,:].h).
// W_hh as fp16: cols 0..447 in 224 VGPRs/thread, cols 448..511 in 64KB LDS.
// h carried as fp16 in a per-batch private double-buffer placed in the d_out
// tail (the h_final slot, overwritten at t=2047). No inter-WG communication.
// ---------------------------------------------------------------------------
__global__ __launch_bounds__(512, 2) void rnn_scan(
    const float* __restrict__ h0,   // [64, 512]
    const float* __restrict__ Whh,  // [512, 512]
    const float* __restrict__ bhh,  // [512]
    float* __restrict__ out)        // [B*S*H + B*H]
{
    __shared__ uint4v WL[8 * 512];  // exactly 64 KB: k = 448..511 for all j

    const int b = blockIdx.x;
    const int j = threadIdx.x;

    // --- load W row j: 224 fp16-pairs to regs, 8 chunks to LDS ---
    unsigned int w[224];
    const float* wp = Whh + (size_t)j * 512;
#pragma unroll
    for (int c = 0; c < 56; ++c) {
        float4v f0 = *(const float4v*)(wp + c * 8);
        float4v f1 = *(const float4v*)(wp + c * 8 + 4);
        w[c * 4 + 0] = pk2(f0.x, f0.y);
        w[c * 4 + 1] = pk2(f0.z, f0.w);
        w[c * 4 + 2] = pk2(f1.x, f1.y);
        w[c * 4 + 3] = pk2(f1.z, f1.w);
    }
#pragma unroll
    for (int c = 0; c < 8; ++c) {
        float4v f0 = *(const float4v*)(wp + 448 + c * 8);
        float4v f1 = *(const float4v*)(wp + 448 + c * 8 + 4);
        WL[c * 512 + j] = pack8(f0, f1);
    }
    const float bj = bhh[j];

    // per-batch private fp16 staging inside this batch's h_final slot (2048 B)
    ushort_t* stage = (ushort_t*)(out + (size_t)B_ * S_ * H_) + b * 1024;
    stage[j] = (ushort_t)pk2(h0[b * 512 + j], 0.f);  // buf0 <- h0
    __syncthreads();

    float* outb = out + (size_t)b * S_ * H_ + j;
    float* tail = out + (size_t)B_ * S_ * H_ + b * 512 + j;

    for (int t = 0; t < S_; ++t) {
        const uint4v* hsrc = (const uint4v*)(stage + (t & 1) * 512);  // 64 chunks
        float xpv = outb[(size_t)t * 512];  // prefetch early; own address only
        float a0 = 0.f, a1 = 0.f, a2 = 0.f, a3 = 0.f;
#pragma unroll
        for (int c = 0; c < 56; ++c) {
            uint4v hh = hsrc[c];  // uniform address -> L1-resident broadcast
            a0 = fdot2u(hh.x, w[c * 4 + 0], a0);
            a1 = fdot2u(hh.y, w[c * 4 + 1], a1);
            a2 = fdot2u(hh.z, w[c * 4 + 2], a2);
            a3 = fdot2u(hh.w, w[c * 4 + 3], a3);
        }
#pragma unroll
        for (int c = 0; c < 8; ++c) {
            uint4v hh = hsrc[56 + c];
            uint4v wv = WL[c * 512 + j];
            a0 = fdot2u(hh.x, wv.x, a0);
            a1 = fdot2u(hh.y, wv.y, a1);
            a2 = fdot2u(hh.z, wv.z, a2);
            a3 = fdot2u(hh.w, wv.w, a3);
        }
        float y = (a0 + a1) + (a2 + a3) + xpv + bj;
        float h = tanhf(y);
        outb[(size_t)t * 512] = h;  // overwrite xp slot with h (output)
        if (t < S_ - 1) {
            stage[((t + 1) & 1) * 512 + j] = (ushort_t)pk2(h, 0.f);
        } else {
            __syncthreads();  // all lanes done reading buf before h_final clobbers it
            *tail = h;
        }
        __syncthreads();  // step-t staging stores visible before step-t+1 reads
    }
}

extern "C" void kernel_launch(void* const* d_in, const int* in_sizes, int n_in,
                              void* d_out, int out_size, void* d_ws, size_t ws_size,
                              hipStream_t stream) {
    const float* inputs = (const float*)d_in[0];
    const float* h0     = (const float*)d_in[1];
    const float* W_ih   = (const float*)d_in[2];
    const float* W_hh   = (const float*)d_in[3];
    const float* b_ih   = (const float*)d_in[4];
    const float* b_hh   = (const float*)d_in[5];
    float* out = (float*)d_out;

    // 1) xp = inputs @ W_ih^T + b_ih  -> staged into d_out
    hipLaunchKernelGGL(xproj_gemm, dim3(131072 / 64), dim3(256), 0, stream,
                       inputs, W_ih, b_ih, out);
    // 2) sequential scan, overwrites xp slots with h, writes h_final tail
    hipLaunchKernelGGL(rnn_scan, dim3(B_), dim3(512), 0, stream,
                       h0, W_hh, b_hh, out);
}

// Round 2
// 6833.907 us; speedup vs baseline: 1.4770x; 1.4770x over previous
//
#include <hip/hip_runtime.h>

#define B_ 64
#define S_ 2048
#define I_ 512
#define H_ 512

typedef _Float16 half2v __attribute__((ext_vector_type(2)));
typedef _Float16 half8v __attribute__((ext_vector_type(8)));
typedef float    float4v __attribute__((ext_vector_type(4)));
typedef unsigned int uint4v __attribute__((ext_vector_type(4)));
typedef unsigned short ushort_t;

__device__ inline unsigned int pk2(float a, float b) {
    // v_cvt_pkrtz_f16_f32: pack (a->low, b->high)
    return __builtin_bit_cast(unsigned int, __builtin_amdgcn_cvt_pkrtz(a, b));
}

__device__ inline uint4v pack8(float4v a, float4v b) {
    uint4v r;
    r.x = pk2(a.x, a.y);
    r.y = pk2(a.z, a.w);
    r.z = pk2(b.x, b.y);
    r.w = pk2(b.z, b.w);
    return r;
}

__device__ inline float fdot2u(unsigned int h2, unsigned int w2, float acc) {
    return __builtin_amdgcn_fdot2(__builtin_bit_cast(half2v, h2),
                                  __builtin_bit_cast(half2v, w2), acc, false);
}

// ---------------------------------------------------------------------------
// Kernel 1: xp[m, n] = sum_k inputs[m, k] * W_ih[n, k] + b_ih[n]
// M = 131072, N = 512, K = 512.  Unchanged from round 1 (~470 us, 2nd-order).
// ---------------------------------------------------------------------------
__global__ __launch_bounds__(256, 2) void xproj_gemm(
    const float* __restrict__ A,    // [131072, 512] inputs
    const float* __restrict__ Bw,   // [512, 512]    W_ih
    const float* __restrict__ bias, // [512]         b_ih
    float* __restrict__ C)          // [131072, 512] -> d_out
{
    __shared__ uint4v As[64 * 5];
    __shared__ uint4v Bs[512 * 5];

    const int tid  = threadIdx.x;
    const int wave = tid >> 6;
    const int lane = tid & 63;
    const int lm   = lane & 15;
    const int lq   = lane >> 4;
    const int m0   = blockIdx.x * 64;
    const int nb   = wave * 128;

    float4v acc[4][8];
#pragma unroll
    for (int mf = 0; mf < 4; ++mf)
#pragma unroll
        for (int nf = 0; nf < 8; ++nf)
            acc[mf][nf] = (float4v){0.f, 0.f, 0.f, 0.f};

    float biasv[8];
#pragma unroll
    for (int nf = 0; nf < 8; ++nf)
        biasv[nf] = bias[nb + nf * 16 + lm];

    const int sm    = tid >> 2;
    const int skq   = tid & 3;
    const int sslot = skq ^ (sm & 3);

    for (int kt = 0; kt < 16; ++kt) {
        const int k0 = kt * 32;
        const float* ap = A + (size_t)(m0 + sm) * 512 + k0 + skq * 8;
        float4v a0 = *(const float4v*)ap;
        float4v a1 = *(const float4v*)(ap + 4);
        float4v b0[8], b1[8];
#pragma unroll
        for (int i = 0; i < 8; ++i) {
            const float* bp = Bw + (size_t)(sm + 64 * i) * 512 + k0 + skq * 8;
            b0[i] = *(const float4v*)bp;
            b1[i] = *(const float4v*)(bp + 4);
        }
        __syncthreads();
        As[sm * 5 + sslot] = pack8(a0, a1);
#pragma unroll
        for (int i = 0; i < 8; ++i)
            Bs[(sm + 64 * i) * 5 + sslot] = pack8(b0[i], b1[i]);
        __syncthreads();

        half8v af[4];
#pragma unroll
        for (int mf = 0; mf < 4; ++mf) {
            int row = mf * 16 + lm;
            af[mf] = __builtin_bit_cast(half8v, As[row * 5 + (lq ^ (lm & 3))]);
        }
        half8v bfr[8];
#pragma unroll
        for (int nf = 0; nf < 8; ++nf) {
            int row = nb + nf * 16 + lm;
            bfr[nf] = __builtin_bit_cast(half8v, Bs[row * 5 + (lq ^ (lm & 3))]);
        }
#pragma unroll
        for (int mf = 0; mf < 4; ++mf)
#pragma unroll
            for (int nf = 0; nf < 8; ++nf)
                acc[mf][nf] = __builtin_amdgcn_mfma_f32_16x16x32_f16(
                    af[mf], bfr[nf], acc[mf][nf], 0, 0, 0);
    }

#pragma unroll
    for (int mf = 0; mf < 4; ++mf) {
        int mrow = m0 + mf * 16 + lq * 4;
#pragma unroll
        for (int nf = 0; nf < 8; ++nf) {
            float* cp = C + (size_t)mrow * 512 + nb + nf * 16 + lm;
            float4v v = acc[mf][nf];
            cp[0]    = v.x + biasv[nf];
            cp[512]  = v.y + biasv[nf];
            cp[1024] = v.z + biasv[nf];
            cp[1536] = v.w + biasv[nf];
        }
    }
}

// ---------------------------------------------------------------------------
// Kernel 2: sequential scan. One WG per batch: 64 WGs x 1024 threads.
// Thread (j = tid&511, kh = tid>>9) computes the kh-half of row j's dot:
//   y[j] = sum_k W[j,k] h[k];  cols [kh*256, kh*256+256) held as fp16 in
// exactly 128 VGPRs (full register residency of W_hh across the block:
// 1024 thr x 512 B = 512 KB = whole CU register-file weight share).
// h carried fp16 in a 2 KB LDS double buffer (wave-uniform broadcast reads);
// k-half partials combined through a 2 KB LDS fp32 buffer. 2 barriers/step.
// __launch_bounds__(1024, 1): 2nd arg = min BLOCKS/CU (CUDA semantics,
// confirmed by round-1's 128-VGPR cap at (512,2)) -> 256 arch VGPRs avail.
// ---------------------------------------------------------------------------
__global__ __launch_bounds__(1024, 1) void rnn_scan(
    const float* __restrict__ h0,   // [64, 512]
    const float* __restrict__ Whh,  // [512, 512]
    const float* __restrict__ bhh,  // [512]
    float* __restrict__ out)        // [B*S*H + B*H]
{
    __shared__ uint4v stagev[2][64];  // fp16 h, double-buffered (2 KB)
    __shared__ float  part[512];      // kh=1 partial sums (2 KB)

    const int tid = threadIdx.x;
    const int j   = tid & 511;
    const int kh  = tid >> 9;    // wave-uniform (waves 0-7: kh=0, 8-15: kh=1)
    const int b   = blockIdx.x;

    // --- W row-half j, cols [kh*256, kh*256+256), fp16 in 128 VGPRs ---
    unsigned int w[128];
    const float* wp = Whh + (size_t)j * 512 + kh * 256;
#pragma unroll
    for (int c = 0; c < 64; ++c) {
        float4v f = *(const float4v*)(wp + c * 4);
        w[c * 2 + 0] = pk2(f.x, f.y);
        w[c * 2 + 1] = pk2(f.z, f.w);
    }

    float bj = 0.f, xpA = 0.f, xpB = 0.f;
    float* outb = out + (size_t)b * S_ * H_ + j;
    if (kh == 0) {
        ((ushort_t*)stagev)[j] = (ushort_t)pk2(h0[b * 512 + j], 0.f);
        bj  = bhh[j];
        xpA = outb[0];            // xp for t=0
        xpB = outb[512];          // xp for t=1
    }
    __syncthreads();

    for (int t = 0; t < S_; ++t) {
        const uint4v* hs = &stagev[t & 1][kh * 32];
        float a0 = 0.f, a1 = 0.f, a2 = 0.f, a3 = 0.f;
#pragma unroll
        for (int c = 0; c < 32; ++c) {
            uint4v hh = hs[c];    // wave-uniform address -> LDS broadcast
            a0 = fdot2u(hh.x, w[c * 4 + 0], a0);
            a1 = fdot2u(hh.y, w[c * 4 + 1], a1);
            a2 = fdot2u(hh.z, w[c * 4 + 2], a2);
            a3 = fdot2u(hh.w, w[c * 4 + 3], a3);
        }
        float a = (a0 + a1) + (a2 + a3);
        if (kh == 1) part[j] = a;
        __syncthreads();          // B1: partials visible
        if (kh == 0) {
            float y = a + part[j] + ((t & 1) ? xpB : xpA) + bj;
            // tanh(y) = 1 - 2/(exp2(y*2*log2e) + 1); saturates correctly
            float e = __builtin_amdgcn_exp2f(y * 2.88539008f);
            float h = 1.f - 2.f * __builtin_amdgcn_rcpf(e + 1.f);
            outb[(size_t)t * H_] = h;                       // output [b,t,j]
            ((ushort_t*)stagev)[((t + 1) & 1) * 512 + j] = (ushort_t)pk2(h, 0.f);
            // prefetch xp for t+2 (always in-bounds incl. t=2046/2047: lands
            // in next batch / tail region, value discarded)
            float nxt = outb[(size_t)(t + 2) * H_];
            if (t & 1) xpB = nxt; else xpA = nxt;
            if (t == S_ - 1) out[(size_t)B_ * S_ * H_ + b * 512 + j] = h;
        }
        __syncthreads();          // B2: new h staged before next step reads
    }
}

extern "C" void kernel_launch(void* const* d_in, const int* in_sizes, int n_in,
                              void* d_out, int out_size, void* d_ws, size_t ws_size,
                              hipStream_t stream) {
    const float* inputs = (const float*)d_in[0];
    const float* h0     = (const float*)d_in[1];
    const float* W_ih   = (const float*)d_in[2];
    const float* W_hh   = (const float*)d_in[3];
    const float* b_ih   = (const float*)d_in[4];
    const float* b_hh   = (const float*)d_in[5];
    float* out = (float*)d_out;

    // 1) xp = inputs @ W_ih^T + b_ih  -> staged into d_out
    hipLaunchKernelGGL(xproj_gemm, dim3(131072 / 64), dim3(256), 0, stream,
                       inputs, W_ih, b_ih, out);
    // 2) sequential scan, overwrites xp slots with h, writes h_final tail
    hipLaunchKernelGGL(rnn_scan, dim3(B_), dim3(1024), 0, stream,
                       h0, W_hh, b_hh, out);
}